// Round 1
// baseline (369.746 us; speedup 1.0000x reference)
//
#include <hip/hip_runtime.h>
#include <hip/hip_bf16.h>

// SelfAttention: B=16, N=1024, M=1024, D=768, fp32 in/out.
// out[b,n, 0:768]   = input[b,n,:]
// out[b,n,768:1536] = softmax_m( (input*dot_scale) @ memory^T  masked ) @ memory
// NOTE: input_dot (w_in) is constant along the softmax axis -> cancels exactly.

#define B_ 16
#define N_ 1024
#define M_ 1024
#define D_ 768

#define BN 32      // q rows per workgroup
#define BM 64      // m columns per tile
#define QSTR 776   // q_lds row stride in bf16 (768 + 8 pad -> bank spread, 16B aligned)
#define SSTR 65    // s_lds row stride in floats
#define PSTR 72    // p_lds row stride in bf16 (16B aligned, bank spread)

typedef __attribute__((ext_vector_type(8))) short short8;
typedef __attribute__((ext_vector_type(4))) float f32x4;

__device__ __forceinline__ unsigned short f2bf(float x) {
    unsigned int u = __builtin_bit_cast(unsigned int, x);
    u += 0x7FFFu + ((u >> 16) & 1u);   // RNE
    return (unsigned short)(u >> 16);
}

// ---------------------------------------------------------------------------
// prep: memory fp32 -> km bf16 [b][m][d]  and  kmT bf16 [b][d][m]
// grid: B * 16(m-tiles) * 12(d-tiles), 64x64 tiles, 256 threads
// ---------------------------------------------------------------------------
__global__ __launch_bounds__(256)
void prep_kernel(const float* __restrict__ memory,
                 unsigned short* __restrict__ km,
                 unsigned short* __restrict__ kmT)
{
    int bid = blockIdx.x;
    int b   = bid / (16 * 12);
    int rem = bid % (16 * 12);
    int mt  = rem / 12;
    int dt  = rem % 12;
    int tid = threadIdx.x;

    __shared__ unsigned short tile[64][68];

    const float* src = memory + ((size_t)b * M_ + (size_t)mt * 64) * D_ + dt * 64;

#pragma unroll
    for (int i = 0; i < 4; ++i) {
        int j   = tid + 256 * i;
        int row = j >> 4;
        int c4  = j & 15;
        float4 v = *(const float4*)(src + (size_t)row * D_ + c4 * 4);
        unsigned short h0 = f2bf(v.x), h1 = f2bf(v.y), h2 = f2bf(v.z), h3 = f2bf(v.w);
        tile[row][c4 * 4 + 0] = h0;
        tile[row][c4 * 4 + 1] = h1;
        tile[row][c4 * 4 + 2] = h2;
        tile[row][c4 * 4 + 3] = h3;
        uint2 pk;
        pk.x = (unsigned)h0 | ((unsigned)h1 << 16);
        pk.y = (unsigned)h2 | ((unsigned)h3 << 16);
        *(uint2*)(km + ((size_t)b * M_ + (size_t)(mt * 64 + row)) * D_ + dt * 64 + c4 * 4) = pk;
    }
    __syncthreads();
#pragma unroll
    for (int i = 0; i < 4; ++i) {
        int j  = tid + 256 * i;
        int dr = j >> 4;
        int c4 = j & 15;
        unsigned short h0 = tile[c4 * 4 + 0][dr];
        unsigned short h1 = tile[c4 * 4 + 1][dr];
        unsigned short h2 = tile[c4 * 4 + 2][dr];
        unsigned short h3 = tile[c4 * 4 + 3][dr];
        uint2 pk;
        pk.x = (unsigned)h0 | ((unsigned)h1 << 16);
        pk.y = (unsigned)h2 | ((unsigned)h3 << 16);
        *(uint2*)(kmT + ((size_t)b * D_ + (size_t)(dt * 64 + dr)) * M_ + mt * 64 + c4 * 4) = pk;
    }
}

// ---------------------------------------------------------------------------
// attn: flash-style online softmax. One WG = (b, 32-row q strip).
// 4 waves: QK^T -> each wave a 16-wide m chunk; PV -> each wave a 192-wide d chunk.
// ---------------------------------------------------------------------------
__global__ __launch_bounds__(256, 2)
void attn_kernel(const float* __restrict__ input,
                 const int* __restrict__ mask,
                 const float* __restrict__ dot_scale,
                 const unsigned short* __restrict__ km,
                 const unsigned short* __restrict__ kmT,
                 float* __restrict__ out)
{
    int wg  = blockIdx.x;
    int b   = wg >> 5;
    int n0  = (wg & 31) * BN;
    int tid = threadIdx.x;
    int wave = tid >> 6;
    int lane = tid & 63;
    int quad = lane >> 4;
    int l16  = lane & 15;

    __shared__ __align__(16) unsigned short q_lds[BN * QSTR];
    __shared__ float s_lds[BN * SSTR];
    __shared__ __align__(16) unsigned short p_lds[BN * PSTR];
    __shared__ float mrun[BN], lrun[BN], alpha_s[BN];

    const float* inp_b = input + ((size_t)b * N_ + n0) * D_;
    float*       out_b = out + ((size_t)b * N_ + n0) * (2 * D_);

    // ---- stage Q (scaled -> bf16 LDS) + pass-through copy of input to out
    {
        int srow = tid >> 3;   // 0..31, 8 threads per row
        int si   = tid & 7;
        const float4* inrow  = (const float4*)(inp_b + (size_t)srow * D_);
        float4*       outrow = (float4*)(out_b + (size_t)srow * 2 * D_);
        unsigned short* qrow = q_lds + srow * QSTR;
        const float4* dsv = (const float4*)dot_scale;
#pragma unroll 4
        for (int it = 0; it < 24; ++it) {
            int c4 = si + 8 * it;          // 0..191
            float4 v = inrow[c4];
            outrow[c4] = v;
            float4 ds = dsv[c4];
            qrow[c4 * 4 + 0] = f2bf(v.x * ds.x);
            qrow[c4 * 4 + 1] = f2bf(v.y * ds.y);
            qrow[c4 * 4 + 2] = f2bf(v.z * ds.z);
            qrow[c4 * 4 + 3] = f2bf(v.w * ds.w);
        }
        if (tid < BN) { mrun[tid] = -1e30f; lrun[tid] = 0.f; }
    }
    __syncthreads();

    f32x4 acc[2][12];
#pragma unroll
    for (int rb = 0; rb < 2; ++rb)
#pragma unroll
        for (int df = 0; df < 12; ++df)
            acc[rb][df] = (f32x4){0.f, 0.f, 0.f, 0.f};

    const unsigned short* km_b  = km  + (size_t)b * M_ * D_;
    const unsigned short* kmT_b = kmT + (size_t)b * D_ * M_;
    const int* mask_b = mask + b * M_;

    for (int mt = 0; mt < 16; ++mt) {
        int m0 = mt * BM;

        // ---- QK^T: this wave computes S[0:32][m0+wave*16 .. +16] over K=768
        f32x4 s0 = (f32x4){0.f, 0.f, 0.f, 0.f};
        f32x4 s1 = s0;
        {
            const unsigned short* krow  = km_b + (size_t)(m0 + wave * 16 + l16) * D_ + quad * 8;
            const unsigned short* qrow0 = q_lds + l16 * QSTR + quad * 8;
            const unsigned short* qrow1 = qrow0 + 16 * QSTR;
#pragma unroll
            for (int kc = 0; kc < 24; ++kc) {
                short8 bf = *(const short8*)(krow + kc * 32);
                short8 a0 = *(const short8*)(qrow0 + kc * 32);
                short8 a1 = *(const short8*)(qrow1 + kc * 32);
                s0 = __builtin_amdgcn_mfma_f32_16x16x32_bf16(a0, bf, s0, 0, 0, 0);
                s1 = __builtin_amdgcn_mfma_f32_16x16x32_bf16(a1, bf, s1, 0, 0, 0);
            }
        }
        // mask + write S tile (C layout: col=l16, row=quad*4+reg)
        {
            int mv = mask_b[m0 + wave * 16 + l16];
            float* sc = s_lds + wave * 16 + l16;
#pragma unroll
            for (int r = 0; r < 4; ++r) {
                float v0 = (mv != 0) ? s0[r] : -3e38f;
                float v1 = (mv != 0) ? s1[r] : -3e38f;
                sc[(quad * 4 + r) * SSTR]        = v0;
                sc[(16 + quad * 4 + r) * SSTR]   = v1;
            }
        }
        __syncthreads();   // bar1: S visible, prev-iter p_lds reads done

        // ---- online softmax over this 64-col chunk (8 threads per row)
        {
            int trow = tid >> 3;
            int ti   = tid & 7;
            float sv[8];
            float mloc = -3.4e38f;
#pragma unroll
            for (int j = 0; j < 8; ++j) {
                sv[j] = s_lds[trow * SSTR + ti * 8 + j];
                mloc = fmaxf(mloc, sv[j]);
            }
            mloc = fmaxf(mloc, __shfl_xor(mloc, 1));
            mloc = fmaxf(mloc, __shfl_xor(mloc, 2));
            mloc = fmaxf(mloc, __shfl_xor(mloc, 4));
            float mold = mrun[trow];              // same-wave lockstep: read-before-write safe
            float mnew = fmaxf(mold, mloc);       // >= -1e30 always (init), masked tile -> no poison
            float al   = __expf(mold - mnew);
            float psum = 0.f;
            unsigned short* pr = p_lds + trow * PSTR + ti * 8;
#pragma unroll
            for (int j = 0; j < 8; ++j) {
                float p = __expf(sv[j] - mnew);
                psum += p;
                pr[j] = f2bf(p);
            }
            psum += __shfl_xor(psum, 1);
            psum += __shfl_xor(psum, 2);
            psum += __shfl_xor(psum, 4);
            if (ti == 0) {
                mrun[trow]    = mnew;
                lrun[trow]    = lrun[trow] * al + psum;
                alpha_s[trow] = al;
            }
        }
        __syncthreads();   // bar2: P + alpha visible

        // ---- rescale O accumulator, then PV: O[0:32][wave*192 +: 192] += P * V
        {
            float a0[4], a1[4];
#pragma unroll
            for (int r = 0; r < 4; ++r) {
                a0[r] = alpha_s[quad * 4 + r];
                a1[r] = alpha_s[16 + quad * 4 + r];
            }
#pragma unroll
            for (int df = 0; df < 12; ++df)
#pragma unroll
                for (int r = 0; r < 4; ++r) {
                    acc[0][df][r] *= a0[r];
                    acc[1][df][r] *= a1[r];
                }
            const unsigned short* vbase = kmT_b + (size_t)(wave * 192 + l16) * M_ + m0 + quad * 8;
#pragma unroll
            for (int kc = 0; kc < 2; ++kc) {
                short8 pa0 = *(const short8*)(p_lds + l16 * PSTR + kc * 32 + quad * 8);
                short8 pa1 = *(const short8*)(p_lds + (16 + l16) * PSTR + kc * 32 + quad * 8);
#pragma unroll
                for (int df = 0; df < 12; ++df) {
                    short8 bf = *(const short8*)(vbase + (size_t)df * 16 * M_ + kc * 32);
                    acc[0][df] = __builtin_amdgcn_mfma_f32_16x16x32_bf16(pa0, bf, acc[0][df], 0, 0, 0);
                    acc[1][df] = __builtin_amdgcn_mfma_f32_16x16x32_bf16(pa1, bf, acc[1][df], 0, 0, 0);
                }
            }
        }
        // next iter's s_lds write is ordered by bar1; p_lds rewrite by next bar1 too
    }

    // ---- epilogue: O / l  -> out right half
    {
        float li0[4], li1[4];
#pragma unroll
        for (int r = 0; r < 4; ++r) {
            li0[r] = 1.f / lrun[quad * 4 + r];
            li1[r] = 1.f / lrun[16 + quad * 4 + r];
        }
#pragma unroll
        for (int df = 0; df < 12; ++df) {
            int col = D_ + wave * 192 + df * 16 + l16;
#pragma unroll
            for (int r = 0; r < 4; ++r) {
                out_b[(size_t)(quad * 4 + r) * (2 * D_) + col]      = acc[0][df][r] * li0[r];
                out_b[(size_t)(16 + quad * 4 + r) * (2 * D_) + col] = acc[1][df][r] * li1[r];
            }
        }
    }
}

// ---------------------------------------------------------------------------
extern "C" void kernel_launch(void* const* d_in, const int* in_sizes, int n_in,
                              void* d_out, int out_size, void* d_ws, size_t ws_size,
                              hipStream_t stream)
{
    const float* input     = (const float*)d_in[0];
    const float* memory    = (const float*)d_in[1];
    const int*   mask      = (const int*)d_in[2];
    // d_in[3] = w_in: mathematically cancels under softmax (per-row constant) -> unused
    const float* dot_scale = (const float*)d_in[4];
    float* out = (float*)d_out;

    // workspace: km bf16 [B][M][D] then kmT bf16 [B][D][M]  (25.17 MB each)
    unsigned short* km  = (unsigned short*)d_ws;
    unsigned short* kmT = km + (size_t)B_ * M_ * D_;

    prep_kernel<<<dim3(B_ * 16 * 12), dim3(256), 0, stream>>>(memory, km, kmT);
    attn_kernel<<<dim3(B_ * (N_ / BN)), dim3(256), 0, stream>>>(input, mask, dot_scale, km, kmT, out);
}

// Round 2
// 294.825 us; speedup vs baseline: 1.2541x; 1.2541x over previous
//
#include <hip/hip_runtime.h>

// SelfAttention: B=16, N=1024, M=1024, D=768, fp32 in/out.
// out[b,n, 0:768]   = input[b,n,:]
// out[b,n,768:1536] = softmax_m( (input*dot_scale) @ memory^T  masked ) @ memory
// input_dot (w_in) is constant along the softmax axis -> cancels exactly.
// R2: mask-compaction (only ~512 of 1024 memory rows survive), in-register
// softmax (S stays in MFMA C-frags), BM=128 chunks, batch->XCD swizzle.

#define B_ 16
#define N_ 1024
#define M_ 1024
#define D_ 768

#define BN 32      // q rows per workgroup
#define BM 128     // compacted m columns per chunk
#define QSTR 776   // q_lds row stride in bf16 (768+8: bank spread, 16B aligned)
#define PSTR 136   // p_lds row stride in bf16 (128+8: 16B aligned)

typedef __attribute__((ext_vector_type(8))) short short8;
typedef __attribute__((ext_vector_type(4))) float f32x4;

__device__ __forceinline__ unsigned short f2bf(float x) {
    unsigned int u = __builtin_bit_cast(unsigned int, x);
    u += 0x7FFFu + ((u >> 16) & 1u);   // RNE
    return (unsigned short)(u >> 16);
}
__device__ __forceinline__ unsigned pack2(float a, float b) {
    return (unsigned)f2bf(a) | ((unsigned)f2bf(b) << 16);
}

// ---------------------------------------------------------------------------
// gather: compact memory rows where mask==1, convert fp32->bf16, write
//   km  [b][j][d]  (QK^T B-operand layout, j = compacted index)
//   kmT [b][d][j]  (PV  B-operand layout)
// Each block re-derives the compaction for its 64-row window via an in-LDS
// prefix scan of the 4 KB mask row (mask is L3-resident; no midx workspace).
// grid: 16 m-tiles * 12 d-tiles * 16 batches (batch fastest -> XCD affinity)
// ---------------------------------------------------------------------------
__global__ __launch_bounds__(256)
void gather_kernel(const float* __restrict__ memory,
                   const int* __restrict__ mask,
                   unsigned short* __restrict__ km,
                   unsigned short* __restrict__ kmT)
{
    int blk = blockIdx.x;
    int b   = blk & 15;
    int rem = blk >> 4;          // 0..191
    int mt  = rem / 12;
    int dt  = rem - mt * 12;
    int tid  = threadIdx.x;
    int lane = tid & 63;
    int wv   = tid >> 6;

    __shared__ int wt[4];
    __shared__ int loc[64];

    // scan mask row -> cnt + source rows for this block's compacted window
    int4 mv = ((const int4*)(mask + b * M_))[tid];
    int tsum = mv.x + mv.y + mv.z + mv.w;
    int x = tsum;
#pragma unroll
    for (int d = 1; d < 64; d <<= 1) {
        int u = __shfl_up(x, d);
        if (lane >= d) x += u;
    }
    if (lane == 63) wt[wv] = x;
    __syncthreads();
    int cnt = wt[0] + wt[1] + wt[2] + wt[3];
    int m0  = mt * 64;
    int Mp  = ((cnt + BM - 1) / BM) * BM;
    if (m0 >= Mp) return;        // uniform: cnt identical across block

    int base = 0;
    for (int w2 = 0; w2 < wv; ++w2) base += wt[w2];
    int p  = base + x - tsum;    // exclusive prefix = compacted position
    int m1 = m0 + 64;
    if (mv.x) { if (p >= m0 && p < m1) loc[p - m0] = 4 * tid + 0; p++; }
    if (mv.y) { if (p >= m0 && p < m1) loc[p - m0] = 4 * tid + 1; p++; }
    if (mv.z) { if (p >= m0 && p < m1) loc[p - m0] = 4 * tid + 2; p++; }
    if (mv.w) { if (p >= m0 && p < m1) loc[p - m0] = 4 * tid + 3; p++; }
    __syncthreads();

    // 4x4 register-tile gather + transpose (no LDS micro-ops)
    int c = tid & 15, g = tid >> 4;
    int d0 = dt * 64 + g * 4;
    const float* mem_b = memory + (size_t)b * M_ * D_;
    float v[4][4];
#pragma unroll
    for (int r = 0; r < 4; ++r) {
        int j = m0 + 4 * c + r;
        if (j < cnt) {
            float4 t = *(const float4*)(mem_b + (size_t)loc[4 * c + r] * D_ + d0);
            v[r][0] = t.x; v[r][1] = t.y; v[r][2] = t.z; v[r][3] = t.w;
        } else {
            v[r][0] = v[r][1] = v[r][2] = v[r][3] = 0.f;  // zero-pad tail
        }
    }
    unsigned short* km_b  = km  + (size_t)b * M_ * D_;
    unsigned short* kmT_b = kmT + (size_t)b * D_ * M_;
#pragma unroll
    for (int r = 0; r < 4; ++r) {
        uint2 pk; pk.x = pack2(v[r][0], v[r][1]); pk.y = pack2(v[r][2], v[r][3]);
        *(uint2*)(km_b + (size_t)(m0 + 4 * c + r) * D_ + d0) = pk;
    }
#pragma unroll
    for (int rr = 0; rr < 4; ++rr) {
        uint2 pk; pk.x = pack2(v[0][rr], v[1][rr]); pk.y = pack2(v[2][rr], v[3][rr]);
        *(uint2*)(kmT_b + (size_t)(d0 + rr) * M_ + m0 + 4 * c) = pk;
    }
}

// ---------------------------------------------------------------------------
// attn: flash-style online softmax over compacted columns.
// One WG = (b, 32-row q strip); b = blockIdx&15 -> batch pinned to XCD b%8.
// QK^T: wave w owns 32 cols (4 acc chains); softmax entirely in C-frags with
// shfl reductions + 1KB cross-wave combine; PV: wave w owns 192 d-cols.
// 2 barriers per 128-col chunk, ~4-5 chunks total.
// ---------------------------------------------------------------------------
__global__ __launch_bounds__(256, 2)
void attn_kernel(const float* __restrict__ input,
                 const int* __restrict__ mask,
                 const float* __restrict__ dot_scale,
                 const unsigned short* __restrict__ km,
                 const unsigned short* __restrict__ kmT,
                 float* __restrict__ out)
{
    int wg   = blockIdx.x;
    int b    = wg & 15;
    int n0   = (wg >> 4) * BN;
    int tid  = threadIdx.x;
    int wv   = tid >> 6;
    int lane = tid & 63;
    int quad = lane >> 4;
    int l16  = lane & 15;

    __shared__ __align__(16) unsigned short q_lds[BN * QSTR];
    __shared__ __align__(16) unsigned short p_lds[BN * PSTR];
    __shared__ __align__(16) float wmax[BN * 4];   // [row][wave]
    __shared__ __align__(16) float wsum[BN * 4];
    __shared__ int wt[4];

    // ---- cnt = sum(mask[b]) (wave reduce, combined into the staging barrier)
    {
        int4 mv = ((const int4*)(mask + b * M_))[tid];
        int ms = mv.x + mv.y + mv.z + mv.w;
#pragma unroll
        for (int d2 = 1; d2 < 64; d2 <<= 1) ms += __shfl_xor(ms, d2);
        if (lane == 0) wt[wv] = ms;
    }

    const float* inp_b = input + ((size_t)b * N_ + n0) * D_;
    float*       out_b = out + ((size_t)b * N_ + n0) * (2 * D_);

    // ---- stage Q (scaled -> bf16 LDS) + pass-through copy of input
    {
        int srow = tid >> 3;
        int si   = tid & 7;
        const float4* inrow  = (const float4*)(inp_b + (size_t)srow * D_);
        float4*       outrow = (float4*)(out_b + (size_t)srow * 2 * D_);
        unsigned short* qrow = q_lds + srow * QSTR;
        const float4* dsv = (const float4*)dot_scale;
#pragma unroll 4
        for (int it = 0; it < 24; ++it) {
            int c4 = si + 8 * it;
            float4 v = inrow[c4];
            outrow[c4] = v;
            float4 ds = dsv[c4];
            uint2 pk; pk.x = pack2(v.x * ds.x, v.y * ds.y); pk.y = pack2(v.z * ds.z, v.w * ds.w);
            *(uint2*)(qrow + c4 * 4) = pk;
        }
    }
    __syncthreads();
    int cnt = wt[0] + wt[1] + wt[2] + wt[3];
    int nc  = (cnt + BM - 1) / BM;

    f32x4 acc[2][12];
#pragma unroll
    for (int nf = 0; nf < 2; ++nf)
#pragma unroll
        for (int df = 0; df < 12; ++df)
            acc[nf][df] = (f32x4){0.f, 0.f, 0.f, 0.f};
    float mrun[2][4], lrun[2][4];
#pragma unroll
    for (int nf = 0; nf < 2; ++nf)
#pragma unroll
        for (int r = 0; r < 4; ++r) { mrun[nf][r] = -1e30f; lrun[nf][r] = 0.f; }

    const unsigned short* km_b  = km  + (size_t)b * M_ * D_;
    const unsigned short* kmT_b = kmT + (size_t)b * D_ * M_;

    for (int ch = 0; ch < nc; ++ch) {
        int m0 = ch * BM;

        // ---- QK^T: 4 independent chains (2 mfrag x 2 nfrag)
        f32x4 s[2][2];
        s[0][0] = s[0][1] = s[1][0] = s[1][1] = (f32x4){0.f, 0.f, 0.f, 0.f};
        {
            const unsigned short* kb0 = km_b + (size_t)(m0 + wv * 32 + l16) * D_ + quad * 8;
            const unsigned short* kb1 = kb0 + 16 * D_;
            const unsigned short* qr0 = q_lds + l16 * QSTR + quad * 8;
            const unsigned short* qr1 = qr0 + 16 * QSTR;
#pragma unroll
            for (int kc = 0; kc < 24; ++kc) {
                short8 b0 = *(const short8*)(kb0 + kc * 32);
                short8 b1 = *(const short8*)(kb1 + kc * 32);
                short8 a0 = *(const short8*)(qr0 + kc * 32);
                short8 a1 = *(const short8*)(qr1 + kc * 32);
                s[0][0] = __builtin_amdgcn_mfma_f32_16x16x32_bf16(a0, b0, s[0][0], 0, 0, 0);
                s[0][1] = __builtin_amdgcn_mfma_f32_16x16x32_bf16(a0, b1, s[0][1], 0, 0, 0);
                s[1][0] = __builtin_amdgcn_mfma_f32_16x16x32_bf16(a1, b0, s[1][0], 0, 0, 0);
                s[1][1] = __builtin_amdgcn_mfma_f32_16x16x32_bf16(a1, b1, s[1][1], 0, 0, 0);
            }
        }
        // tail mask on compacted col index (km tail rows are zero-padded)
        {
            int col0 = m0 + wv * 32 + l16;
            if (col0 >= cnt) {
#pragma unroll
                for (int r = 0; r < 4; ++r) { s[0][0][r] = -3e38f; s[1][0][r] = -3e38f; }
            }
            if (col0 + 16 >= cnt) {
#pragma unroll
                for (int r = 0; r < 4; ++r) { s[0][1][r] = -3e38f; s[1][1][r] = -3e38f; }
            }
        }
        // ---- in-register row max (over this wave's 32 cols)
        float mx[2][4];
#pragma unroll
        for (int nf = 0; nf < 2; ++nf)
#pragma unroll
            for (int r = 0; r < 4; ++r) {
                float m_ = fmaxf(s[nf][0][r], s[nf][1][r]);
                m_ = fmaxf(m_, __shfl_xor(m_, 1));
                m_ = fmaxf(m_, __shfl_xor(m_, 2));
                m_ = fmaxf(m_, __shfl_xor(m_, 4));
                m_ = fmaxf(m_, __shfl_xor(m_, 8));
                mx[nf][r] = m_;
            }
        if (l16 == 0) {
#pragma unroll
            for (int nf = 0; nf < 2; ++nf)
#pragma unroll
                for (int r = 0; r < 4; ++r)
                    wmax[(nf * 16 + quad * 4 + r) * 4 + wv] = mx[nf][r];
        }
        __syncthreads();   // bar_a: wmax visible (also fences p_lds reuse)

        // ---- cross-wave max -> mnew/alpha (replicated, bitwise-identical)
        float al[2][4];
#pragma unroll
        for (int nf = 0; nf < 2; ++nf)
#pragma unroll
            for (int r = 0; r < 4; ++r) {
                int row = nf * 16 + quad * 4 + r;
                float4 wm = *(const float4*)&wmax[row * 4];
                float mm = fmaxf(fmaxf(wm.x, wm.y), fmaxf(wm.z, wm.w));
                float mnew = fmaxf(mrun[nf][r], mm);
                al[nf][r] = __expf(mrun[nf][r] - mnew);
                mrun[nf][r] = mnew;
            }
        // ---- P = exp(S - mnew) from regs -> p_lds (bf16), psum via shfl
        float ps[2][4];
#pragma unroll
        for (int nf = 0; nf < 2; ++nf)
#pragma unroll
            for (int r = 0; r < 4; ++r) {
                float p0 = __expf(s[nf][0][r] - mrun[nf][r]);
                float p1 = __expf(s[nf][1][r] - mrun[nf][r]);
                int row = nf * 16 + quad * 4 + r;
                p_lds[row * PSTR + wv * 32 + l16]      = f2bf(p0);
                p_lds[row * PSTR + wv * 32 + 16 + l16] = f2bf(p1);
                float t = p0 + p1;
                t += __shfl_xor(t, 1);
                t += __shfl_xor(t, 2);
                t += __shfl_xor(t, 4);
                t += __shfl_xor(t, 8);
                ps[nf][r] = t;
            }
        if (l16 == 0) {
#pragma unroll
            for (int nf = 0; nf < 2; ++nf)
#pragma unroll
                for (int r = 0; r < 4; ++r)
                    wsum[(nf * 16 + quad * 4 + r) * 4 + wv] = ps[nf][r];
        }
        __syncthreads();   // bar_b: p_lds + wsum visible

        // ---- lrun update (must precede next chunk's bar_a)
#pragma unroll
        for (int nf = 0; nf < 2; ++nf)
#pragma unroll
            for (int r = 0; r < 4; ++r) {
                int row = nf * 16 + quad * 4 + r;
                float4 wsv = *(const float4*)&wsum[row * 4];
                lrun[nf][r] = lrun[nf][r] * al[nf][r] + (wsv.x + wsv.y + wsv.z + wsv.w);
            }
        // ---- rescale O, then PV over this 128-col chunk
#pragma unroll
        for (int df = 0; df < 12; ++df)
#pragma unroll
            for (int nf = 0; nf < 2; ++nf)
#pragma unroll
                for (int r = 0; r < 4; ++r)
                    acc[nf][df][r] *= al[nf][r];
        {
            const unsigned short* vb  = kmT_b + (size_t)(wv * 192 + l16) * M_ + m0 + quad * 8;
            const unsigned short* pr0 = p_lds + l16 * PSTR + quad * 8;
            const unsigned short* pr1 = pr0 + 16 * PSTR;
#pragma unroll
            for (int kc = 0; kc < 4; ++kc) {
                short8 pa0 = *(const short8*)(pr0 + kc * 32);
                short8 pa1 = *(const short8*)(pr1 + kc * 32);
#pragma unroll
                for (int df = 0; df < 12; ++df) {
                    short8 bv = *(const short8*)(vb + (size_t)df * 16 * M_ + kc * 32);
                    acc[0][df] = __builtin_amdgcn_mfma_f32_16x16x32_bf16(pa0, bv, acc[0][df], 0, 0, 0);
                    acc[1][df] = __builtin_amdgcn_mfma_f32_16x16x32_bf16(pa1, bv, acc[1][df], 0, 0, 0);
                }
            }
        }
    }

    // ---- epilogue: O / l -> out right half
#pragma unroll
    for (int nf = 0; nf < 2; ++nf) {
        float li[4];
#pragma unroll
        for (int r = 0; r < 4; ++r) li[r] = 1.f / lrun[nf][r];
#pragma unroll
        for (int df = 0; df < 12; ++df) {
            int col = D_ + wv * 192 + df * 16 + l16;
#pragma unroll
            for (int r = 0; r < 4; ++r)
                out_b[(size_t)(nf * 16 + quad * 4 + r) * (2 * D_) + col] = acc[nf][df][r] * li[r];
        }
    }
}

// ---------------------------------------------------------------------------
extern "C" void kernel_launch(void* const* d_in, const int* in_sizes, int n_in,
                              void* d_out, int out_size, void* d_ws, size_t ws_size,
                              hipStream_t stream)
{
    const float* input     = (const float*)d_in[0];
    const float* memory    = (const float*)d_in[1];
    const int*   mask      = (const int*)d_in[2];
    // d_in[3] = w_in: cancels under softmax (constant along softmax axis)
    const float* dot_scale = (const float*)d_in[4];
    float* out = (float*)d_out;

    unsigned short* km  = (unsigned short*)d_ws;                 // [B][M][D] bf16
    unsigned short* kmT = km + (size_t)B_ * M_ * D_;             // [B][D][M] bf16

    gather_kernel<<<dim3(16 * 12 * B_), dim3(256), 0, stream>>>(memory, mask, km, kmT);
    attn_kernel<<<dim3(B_ * (N_ / BN)), dim3(256), 0, stream>>>(input, mask, dot_scale, km, kmT, out);
}